// Round 11
// baseline (6601.373 us; speedup 1.0000x reference)
//
#include <hip/hip_runtime.h>
#include <math.h>

#define BATCH 16
#define TLEN 2048
#define NTOK (BATCH*TLEN)       // 32768
#define DMODEL 160
#define DINNER 320
#define DSTATE 64
#define DTRANK 10
#define XDBL 138                // DT_RANK + 2*D_STATE (logical)
#define DCONV 12
#define PREK 9
#define NBLK 8
#define WPL 197760              // bf16 weights per layer (in 102400 + xp 44160 + out 51200)

typedef __attribute__((ext_vector_type(8))) short short8;
typedef __attribute__((ext_vector_type(4))) float floatx4;

__device__ __forceinline__ float sigmoidf_(float x) { return 1.f / (1.f + __expf(-x)); }
__device__ __forceinline__ unsigned short f2bf(float f) {
  union { float f; unsigned u; } v; v.f = f;
  unsigned r = v.u + 0x7FFF + ((v.u >> 16) & 1);   // round-to-nearest-even
  return (unsigned short)(r >> 16);
}
__device__ __forceinline__ float bf2f(unsigned short s) {
  union { unsigned u; float f; } v; v.u = ((unsigned)s) << 16;
  return v.f;
}
__device__ __forceinline__ float bflo(unsigned u) {
  union { unsigned u; float f; } v; v.u = u << 16; return v.f;
}
__device__ __forceinline__ float bfhi(unsigned u) {
  union { unsigned u; float f; } v; v.u = u & 0xFFFF0000u; return v.f;
}

// ---------------- pre conv (k=9, same pad) + exact GELU ----------------
__global__ __launch_bounds__(256)
void k_preconv(const float* __restrict__ x, const float* __restrict__ w,
               const float* __restrict__ bias, float* __restrict__ h) {
  int gid = blockIdx.x * 256 + threadIdx.x;
  if (gid >= NTOK * DMODEL) return;
  int c = gid % DMODEL;
  int tok = gid / DMODEL;
  int b = tok / TLEN, t = tok % TLEN;
  const float* xb = x + (size_t)b * TLEN;
  float acc = bias[c];
#pragma unroll
  for (int k = 0; k < PREK; ++k) {
    int tp = t + k - PREK / 2;
    float xv = (tp >= 0 && tp < TLEN) ? xb[tp] : 0.f;
    acc = fmaf(w[c * PREK + k], xv, acc);
  }
  h[gid] = 0.5f * acc * (1.f + erff(acc * 0.70710678118654752440f));
}

// ---------------- ALL-layer weight cast to bf16 (hoisted; grid = NBLK x 773) ----------------
__global__ __launch_bounds__(256)
void k_cast(const float* __restrict__ iw, const float* __restrict__ xw,
            const float* __restrict__ ow, unsigned short* __restrict__ wbf) {
  int L = blockIdx.x / 773;
  int i = (blockIdx.x % 773) * 256 + threadIdx.x;
  unsigned short* wl = wbf + (size_t)L * WPL;
  if (i < 102400) wl[i] = f2bf(iw[(size_t)L * 102400 + i]);
  else if (i < 146560) wl[i] = f2bf(xw[(size_t)L * 44160 + i - 102400]);
  else if (i < WPL) wl[i] = f2bf(ow[(size_t)L * 51200 + i - 146560]);
}

// ---------------- LayerNorm over d=160 -> bf16 out ----------------
__global__ __launch_bounds__(256)
void k_ln(const float* __restrict__ h, const float* __restrict__ g,
          const float* __restrict__ bb, unsigned short* __restrict__ y) {
  int row = blockIdx.x * 4 + (threadIdx.x >> 6);
  int lane = threadIdx.x & 63;
  const float* hr = h + (size_t)row * DMODEL;
  float v0 = hr[lane], v1 = hr[lane + 64];
  float v2 = (lane < DMODEL - 128) ? hr[lane + 128] : 0.f;
  float s = v0 + v1 + v2;
  float sq = v0 * v0 + v1 * v1 + v2 * v2;
#pragma unroll
  for (int off = 32; off; off >>= 1) {
    s += __shfl_xor(s, off);
    sq += __shfl_xor(sq, off);
  }
  float mean = s * (1.f / DMODEL);
  float var = sq * (1.f / DMODEL) - mean * mean;
  float rstd = rsqrtf(var + 1e-5f);
  unsigned short* yr = y + (size_t)row * DMODEL;
  yr[lane] = f2bf((v0 - mean) * rstd * g[lane] + bb[lane]);
  yr[lane + 64] = f2bf((v1 - mean) * rstd * g[lane + 64] + bb[lane + 64]);
  if (lane < DMODEL - 128)
    yr[lane + 128] = f2bf((v2 - mean) * rstd * g[lane + 128] + bb[lane + 128]);
}

// ------- in_proj MFMA GEMM: A_bf[M,160] @ W_bf[640,160]^T -> x fp32, z bf16 -------
__global__ __launch_bounds__(256)
void k_mm_in(const unsigned short* __restrict__ A, const unsigned short* __restrict__ Wb,
             float* __restrict__ xout, unsigned short* __restrict__ zout) {
  __shared__ short As[128 * 40];
  __shared__ short Ws[128 * 40];
  int tid = threadIdx.x;
  int m0 = blockIdx.y * 128, n0 = blockIdx.x * 128;
  int w = tid >> 6, lane = tid & 63;
  int rm = (w >> 1) * 64, cn = (w & 1) * 64;
  int lm = lane & 15, quad = lane >> 4;
  int r = tid >> 1, seg = tid & 1;
  const unsigned short* pA = A + (size_t)(m0 + r) * DMODEL + seg * 16;
  const unsigned short* pW = Wb + (size_t)(n0 + r) * DMODEL + seg * 16;
  floatx4 acc[4][4];
#pragma unroll
  for (int i = 0; i < 4; ++i)
#pragma unroll
    for (int j = 0; j < 4; ++j)
      acc[i][j] = (floatx4){0.f, 0.f, 0.f, 0.f};
  for (int kt = 0; kt < 5; ++kt) {
    uint4 a0 = *(const uint4*)(pA + kt * 32);
    uint4 a1 = *(const uint4*)(pA + kt * 32 + 8);
    uint4 w0 = *(const uint4*)(pW + kt * 32);
    uint4 w1 = *(const uint4*)(pW + kt * 32 + 8);
    *(short8*)&As[r * 40 + seg * 16]     = *(short8*)&a0;
    *(short8*)&As[r * 40 + seg * 16 + 8] = *(short8*)&a1;
    *(short8*)&Ws[r * 40 + seg * 16]     = *(short8*)&w0;
    *(short8*)&Ws[r * 40 + seg * 16 + 8] = *(short8*)&w1;
    __syncthreads();
    short8 af[4], wf[4];
#pragma unroll
    for (int i = 0; i < 4; ++i)
      af[i] = *(short8*)&As[(rm + i * 16 + lm) * 40 + quad * 8];
#pragma unroll
    for (int j = 0; j < 4; ++j)
      wf[j] = *(short8*)&Ws[(cn + j * 16 + lm) * 40 + quad * 8];
#pragma unroll
    for (int i = 0; i < 4; ++i)
#pragma unroll
      for (int j = 0; j < 4; ++j)
        acc[i][j] = __builtin_amdgcn_mfma_f32_16x16x32_bf16(af[i], wf[j], acc[i][j], 0, 0, 0);
    __syncthreads();
  }
#pragma unroll
  for (int i = 0; i < 4; ++i)
#pragma unroll
    for (int reg = 0; reg < 4; ++reg) {
      int m = m0 + rm + i * 16 + quad * 4 + reg;
#pragma unroll
      for (int j = 0; j < 4; ++j) {
        int n = n0 + cn + j * 16 + lm;
        float v = acc[i][j][reg];
        if (n < DINNER) xout[(size_t)m * DINNER + n] = v;
        else zout[(size_t)m * DINNER + n - DINNER] = f2bf(v);
      }
    }
}

// ------- out_proj MFMA GEMM: A_bf[M,K] @ W_bf[N,K]^T (+resid) -> C fp32 [M,N] -------
__global__ __launch_bounds__(256)
void k_mm_g(const unsigned short* __restrict__ A, const unsigned short* __restrict__ Wb,
            float* __restrict__ C, const float* __restrict__ resid, int N, int K) {
  __shared__ short As[128 * 40];
  __shared__ short Ws[64 * 40];
  int tid = threadIdx.x;
  int m0 = blockIdx.y * 128, n0 = blockIdx.x * 64;
  int w = tid >> 6, lane = tid & 63;
  int rm = w * 32;
  int lm = lane & 15, quad = lane >> 4;
  int r = tid >> 1, seg = tid & 1;
  int wr = tid >> 2, wseg = tid & 3;
  bool wvld = (n0 + wr) < N;
  const unsigned short* pA = A + (size_t)(m0 + r) * K + seg * 16;
  const unsigned short* pW = Wb + (size_t)(wvld ? (n0 + wr) : 0) * K + wseg * 8;
  floatx4 acc[2][4];
#pragma unroll
  for (int i = 0; i < 2; ++i)
#pragma unroll
    for (int j = 0; j < 4; ++j)
      acc[i][j] = (floatx4){0.f, 0.f, 0.f, 0.f};
  int nk = K >> 5;
  for (int kt = 0; kt < nk; ++kt) {
    uint4 a0 = *(const uint4*)(pA + kt * 32);
    uint4 a1 = *(const uint4*)(pA + kt * 32 + 8);
    uint4 wv = wvld ? *(const uint4*)(pW + kt * 32)
                    : make_uint4(0u, 0u, 0u, 0u);
    *(short8*)&As[r * 40 + seg * 16]     = *(short8*)&a0;
    *(short8*)&As[r * 40 + seg * 16 + 8] = *(short8*)&a1;
    *(short8*)&Ws[wr * 40 + wseg * 8]    = *(short8*)&wv;
    __syncthreads();
    short8 af[2], wf[4];
#pragma unroll
    for (int i = 0; i < 2; ++i)
      af[i] = *(short8*)&As[(rm + i * 16 + lm) * 40 + quad * 8];
#pragma unroll
    for (int j = 0; j < 4; ++j)
      wf[j] = *(short8*)&Ws[(j * 16 + lm) * 40 + quad * 8];
#pragma unroll
    for (int i = 0; i < 2; ++i)
#pragma unroll
      for (int j = 0; j < 4; ++j)
        acc[i][j] = __builtin_amdgcn_mfma_f32_16x16x32_bf16(af[i], wf[j], acc[i][j], 0, 0, 0);
    __syncthreads();
  }
#pragma unroll
  for (int i = 0; i < 2; ++i)
#pragma unroll
    for (int reg = 0; reg < 4; ++reg) {
      int m = m0 + rm + i * 16 + quad * 4 + reg;
#pragma unroll
      for (int j = 0; j < 4; ++j) {
        int n = n0 + j * 16 + lm;
        if (n < N) {
          float v = acc[i][j][reg];
          if (resid) v += resid[(size_t)m * N + n];
          C[(size_t)m * N + n] = v;
        }
      }
    }
}

// ------- xproj MFMA GEMM -> dt_bf[tok][12] bf16 + B_plane/C_plane fp32 [tok][64] -------
__global__ __launch_bounds__(256)
void k_mm_x(const unsigned short* __restrict__ A, const unsigned short* __restrict__ Wb,
            unsigned short* __restrict__ dtb, float* __restrict__ Bp,
            float* __restrict__ Cp) {
  const int N = XDBL, K = DINNER;
  __shared__ short As[128 * 40];
  __shared__ short Ws[64 * 40];
  int tid = threadIdx.x;
  int m0 = blockIdx.y * 128, n0 = blockIdx.x * 64;
  int w = tid >> 6, lane = tid & 63;
  int rm = w * 32;
  int lm = lane & 15, quad = lane >> 4;
  int r = tid >> 1, seg = tid & 1;
  int wr = tid >> 2, wseg = tid & 3;
  bool wvld = (n0 + wr) < N;
  const unsigned short* pA = A + (size_t)(m0 + r) * K + seg * 16;
  const unsigned short* pW = Wb + (size_t)(wvld ? (n0 + wr) : 0) * K + wseg * 8;
  floatx4 acc[2][4];
#pragma unroll
  for (int i = 0; i < 2; ++i)
#pragma unroll
    for (int j = 0; j < 4; ++j)
      acc[i][j] = (floatx4){0.f, 0.f, 0.f, 0.f};
  int nk = K >> 5;
  for (int kt = 0; kt < nk; ++kt) {
    uint4 a0 = *(const uint4*)(pA + kt * 32);
    uint4 a1 = *(const uint4*)(pA + kt * 32 + 8);
    uint4 wv = wvld ? *(const uint4*)(pW + kt * 32)
                    : make_uint4(0u, 0u, 0u, 0u);
    *(short8*)&As[r * 40 + seg * 16]     = *(short8*)&a0;
    *(short8*)&As[r * 40 + seg * 16 + 8] = *(short8*)&a1;
    *(short8*)&Ws[wr * 40 + wseg * 8]    = *(short8*)&wv;
    __syncthreads();
    short8 af[2], wf[4];
#pragma unroll
    for (int i = 0; i < 2; ++i)
      af[i] = *(short8*)&As[(rm + i * 16 + lm) * 40 + quad * 8];
#pragma unroll
    for (int j = 0; j < 4; ++j)
      wf[j] = *(short8*)&Ws[(j * 16 + lm) * 40 + quad * 8];
#pragma unroll
    for (int i = 0; i < 2; ++i)
#pragma unroll
      for (int j = 0; j < 4; ++j)
        acc[i][j] = __builtin_amdgcn_mfma_f32_16x16x32_bf16(af[i], wf[j], acc[i][j], 0, 0, 0);
    __syncthreads();
  }
#pragma unroll
  for (int i = 0; i < 2; ++i)
#pragma unroll
    for (int reg = 0; reg < 4; ++reg) {
      int m = m0 + rm + i * 16 + quad * 4 + reg;
#pragma unroll
      for (int j = 0; j < 4; ++j) {
        int n = n0 + j * 16 + lm;
        if (n < N) {
          float v = acc[i][j][reg];
          if (n < DTRANK) dtb[(size_t)m * 12 + n] = f2bf(v);
          else if (n < DTRANK + DSTATE) Bp[(size_t)m * DSTATE + n - DTRANK] = v;
          else Cp[(size_t)m * DSTATE + n - DTRANK - DSTATE] = v;
        }
      }
    }
}

// ---- depthwise causal conv (k=12) + SiLU: xbuf[tok][d] -> u_bf token-major + uT_bf time-major ----
__global__ __launch_bounds__(256)
void k_convT(const float* __restrict__ xbuf, const float* __restrict__ cw,
             const float* __restrict__ cb, unsigned short* __restrict__ uTb,
             unsigned short* __restrict__ ubf) {
  int t0 = blockIdx.x * 64, d0 = blockIdx.y * 64, b = blockIdx.z;
  __shared__ float xs[76 * 65];
  __shared__ float us[64 * 65];
  int tid = threadIdx.x, j = tid & 63, w = tid >> 6;
#pragma unroll
  for (int it = 0; it < 19; ++it) {
    int r = it * 4 + w;
    int t = t0 - (DCONV - 1) + r;
    xs[r * 65 + j] = (t >= 0 && t < TLEN)
        ? xbuf[((size_t)b * TLEN + t) * DINNER + d0 + j] : 0.f;
  }
  __syncthreads();
  float cwr[DCONV];
#pragma unroll
  for (int k = 0; k < DCONV; ++k) cwr[k] = cw[(d0 + j) * DCONV + k];
  float cbv = cb[d0 + j];
#pragma unroll
  for (int it = 0; it < 16; ++it) {
    int tl = it * 4 + w;
    float acc = cbv;
#pragma unroll
    for (int k = 0; k < DCONV; ++k)
      acc = fmaf(cwr[k], xs[(tl + k) * 65 + j], acc);
    us[tl * 65 + j] = acc * sigmoidf_(acc);
  }
  __syncthreads();
#pragma unroll
  for (int it = 0; it < 16; ++it) {
    int tr = it * 4 + w;
    ubf[((size_t)b * TLEN + t0 + tr) * DINNER + d0 + j] = f2bf(us[tr * 65 + j]);
  }
#pragma unroll
  for (int it = 0; it < 16; ++it) {
    int dl = it * 4 + w;
    uTb[((size_t)b * DINNER + d0 + dl) * TLEN + t0 + j] = f2bf(us[j * 65 + dl]);
  }
}

// ---- pack v2: qT = {del, del*u} float2 time-major; eT = {skip | ssz<<16} uint ----
__global__ __launch_bounds__(256)
void k_pack(const unsigned short* __restrict__ zbuf, const unsigned short* __restrict__ dtbf,
            const unsigned short* __restrict__ uTb,
            const float* __restrict__ dtw, const float* __restrict__ dtb,
            const float* __restrict__ Dskip,
            float2* __restrict__ qT, unsigned* __restrict__ eT) {
  int t0 = blockIdx.x * 64, d0 = blockIdx.y * 64, b = blockIdx.z;
  __shared__ float zs[64 * 65];
  __shared__ float xd[64 * 13];
  int tid = threadIdx.x, j = tid & 63, w = tid >> 6;
#pragma unroll
  for (int it = 0; it < 16; ++it) {
    int i = it * 4 + w;
    zs[i * 65 + j] = bf2f(zbuf[((size_t)b * TLEN + t0 + i) * DINNER + d0 + j]);
  }
  {
    int r = tid >> 2, c = tid & 3;
    size_t rowb = ((size_t)b * TLEN + t0 + r) * 12;
    for (int cc = c; cc < DTRANK; cc += 4)
      xd[r * 13 + cc] = bf2f(dtbf[rowb + cc]);
  }
  __syncthreads();
#pragma unroll
  for (int it = 0; it < 16; ++it) {
    int dl = it * 4 + w, d = d0 + dl;
    float acc = dtb[d];
    const float* wr = dtw + d * DTRANK;
#pragma unroll
    for (int rr = 0; rr < DTRANK; ++rr)
      acc = fmaf(xd[j * 13 + rr], wr[rr], acc);
    float del = (acc > 20.f) ? acc : log1pf(__expf(acc));
    size_t o = ((size_t)b * DINNER + d) * TLEN + t0 + j;
    float uv = bf2f(uTb[o]);
    float zv = zs[j * 65 + dl];
    float ssz = zv * sigmoidf_(zv);
    qT[o] = make_float2(del, del * uv);
    unsigned lo = f2bf(uv * Dskip[d] * ssz);
    unsigned hi = f2bf(ssz);
    eT[o] = lo | (hi << 16);
  }
}

// ---------------- selective scan: wave per (b,d), lane = state; no barriers ----------------
// Per t: b64 q broadcast + 2 coalesced fp32 plane loads (B,C); 4 VALU + exp2 + ds_write.
__global__ __launch_bounds__(256)
void k_scan(const float2* __restrict__ qT, const unsigned* __restrict__ eT,
            const float* __restrict__ Bp, const float* __restrict__ Cp,
            const float* __restrict__ Alog, unsigned short* __restrict__ yTb) {
  int wave = threadIdx.x >> 6, lane = threadIdx.x & 63;
  int b = blockIdx.x / (DINNER / 4);
  int d = (blockIdx.x % (DINNER / 4)) * 4 + wave;
  __shared__ float ps_all[4][16 * 68];
  float* ps = ps_all[wave];               // per-wave region; same-wave DS ops are ordered
  float Al2 = -__expf(Alog[d * DSTATE + lane]) * 1.44269504088896340736f;
  size_t chan = ((size_t)b * DINNER + d) * TLEN;
  const float2* pq = qT + chan;
  const unsigned* pe = eT + chan;
  unsigned short* py = yTb + chan;
  const float* pB = Bp + ((size_t)b * TLEN) * DSTATE + lane;
  const float* pC = Cp + ((size_t)b * TLEN) * DSTATE + lane;
  float h = 0.f;
  int tl = lane & 15, qq = lane >> 4;
  for (int t0 = 0; t0 < TLEN; t0 += 16) {
#pragma unroll
    for (int t = 0; t < 16; ++t) {
      float2 q = pq[t0 + t];
      float Bv = pB[(size_t)(t0 + t) * DSTATE];
      float Cv = pC[(size_t)(t0 + t) * DSTATE];
      h = fmaf(h, exp2f(q.x * Al2), q.y * Bv);
      ps[t * 68 + lane] = h * Cv;
    }
    float p = 0.f;
    const floatx4* pr = (const floatx4*)&ps[tl * 68 + qq * 16];
#pragma unroll
    for (int i = 0; i < 4; ++i) {
      floatx4 v = pr[i];
      p += v[0] + v[1] + v[2] + v[3];
    }
    p += __shfl_xor(p, 16);
    p += __shfl_xor(p, 32);
    if (lane < 16) {
      int t = t0 + tl;
      unsigned e = pe[t];
      py[t] = f2bf(fmaf(p, bfhi(e), bflo(e)));
    }
  }
}

// ---- transpose yT_bf[b][d][t] -> y_bf[tok][d] (bf16 -> bf16) ----
__global__ __launch_bounds__(256)
void k_t2b(const unsigned short* __restrict__ yTb, unsigned short* __restrict__ ybf) {
  int t0 = blockIdx.x * 64, d0 = blockIdx.y * 64, b = blockIdx.z;
  __shared__ unsigned short ls[64 * 66];
  int tid = threadIdx.x, j = tid & 63, w = tid >> 6;
#pragma unroll
  for (int it = 0; it < 16; ++it) {
    int dl = it * 4 + w;
    ls[dl * 66 + j] = yTb[((size_t)b * DINNER + d0 + dl) * TLEN + t0 + j];
  }
  __syncthreads();
#pragma unroll
  for (int it = 0; it < 16; ++it) {
    int tr = it * 4 + w;
    ybf[((size_t)b * TLEN + t0 + tr) * DINNER + d0 + j] = ls[j * 66 + tr];
  }
}

// ---------------- head ----------------
__global__ __launch_bounds__(256)
void k_head(const float* __restrict__ h, const float* __restrict__ hw,
            const float* __restrict__ hb, float* __restrict__ out) {
  int tok = blockIdx.x * 4 + (threadIdx.x >> 6);
  int lane = threadIdx.x & 63;
  const float* hr = h + (size_t)tok * DMODEL;
  float s = hr[lane] * hw[lane] + hr[lane + 64] * hw[lane + 64];
  if (lane < DMODEL - 128) s += hr[lane + 128] * hw[lane + 128];
#pragma unroll
  for (int off = 32; off; off >>= 1) s += __shfl_xor(s, off);
  if (lane == 0) out[tok] = s + hb[0];
}

extern "C" void kernel_launch(void* const* d_in, const int* in_sizes, int n_in,
                              void* d_out, int out_size, void* d_ws, size_t ws_size,
                              hipStream_t stream) {
  const float* x      = (const float*)d_in[0];
  const float* pre_w  = (const float*)d_in[1];
  const float* pre_b  = (const float*)d_in[2];
  const float* ln_g   = (const float*)d_in[3];
  const float* ln_b   = (const float*)d_in[4];
  const float* in_w   = (const float*)d_in[5];
  const float* conv_w = (const float*)d_in[6];
  const float* conv_b = (const float*)d_in[7];
  const float* xproj_w= (const float*)d_in[8];
  const float* dt_w   = (const float*)d_in[9];
  const float* dt_b   = (const float*)d_in[10];
  const float* A_log  = (const float*)d_in[11];
  const float* D_skip = (const float*)d_in[12];
  const float* out_w  = (const float*)d_in[13];
  const float* head_w = (const float*)d_in[14];
  const float* head_b = (const float*)d_in[15];
  float* out = (float*)d_out;

  // workspace (float units), total 52.37M f = 209.5 MB (< proven 209.7):
  // h | Bp | Cp | dt_bf | qT (also lnxd_bf/u_bf before pack) | uT_bf |
  // X (xbuf fp32 -> eT -> y_bf) | Y (zbuf_bf -> yT_bf) | wbf (all layers)
  float* ws = (float*)d_ws;
  float* h    = ws;
  float* Bp   = h + (size_t)NTOK * DMODEL;
  float* Cp   = Bp + (size_t)NTOK * DSTATE;
  unsigned short* dt_bf = (unsigned short*)(Cp + (size_t)NTOK * DSTATE);
  float2* qT  = (float2*)(dt_bf + (size_t)NTOK * 12);
  unsigned short* uT_bf = (unsigned short*)(qT + (size_t)NTOK * DINNER);
  float* X    = (float*)(uT_bf + (size_t)NTOK * DINNER);
  float* Y    = X + (size_t)NTOK * DINNER;
  unsigned short* wbf = (unsigned short*)(Y + (size_t)NTOK * DINNER / 2);

  unsigned short* lnxd_bf = (unsigned short*)qT;   // dead before pack writes qT
  unsigned short* u_bf    = (unsigned short*)qT;   // dead before pack writes qT
  float*          xbuf    = X;
  unsigned*       eT      = (unsigned*)X;          // xbuf dead after convT
  unsigned short* y_bf    = (unsigned short*)X;    // eT dead after scan
  unsigned short* zbuf_bf = (unsigned short*)Y;
  unsigned short* yT_bf   = (unsigned short*)Y;    // zbuf dead after pack

  k_preconv<<<NTOK * DMODEL / 256, 256, 0, stream>>>(x, pre_w, pre_b, h);
  k_cast<<<NBLK * 773, 256, 0, stream>>>(in_w, xproj_w, out_w, wbf);

  for (int L = 0; L < NBLK; ++L) {
    unsigned short* w_in = wbf + (size_t)L * WPL;
    unsigned short* w_xp = w_in + 102400;
    unsigned short* w_ou = w_in + 146560;
    k_ln<<<NTOK / 4, 256, 0, stream>>>(h, ln_g + L * DMODEL, ln_b + L * DMODEL, lnxd_bf);
    k_mm_in<<<dim3(5, NTOK / 128), 256, 0, stream>>>(lnxd_bf, w_in, xbuf, zbuf_bf);
    k_convT<<<dim3(TLEN / 64, DINNER / 64, BATCH), 256, 0, stream>>>(
        xbuf, conv_w + (size_t)L * DINNER * DCONV, conv_b + (size_t)L * DINNER,
        uT_bf, u_bf);
    k_mm_x<<<dim3(3, NTOK / 128), 256, 0, stream>>>(u_bf, w_xp, dt_bf, Bp, Cp);
    k_pack<<<dim3(TLEN / 64, DINNER / 64, BATCH), 256, 0, stream>>>(
        zbuf_bf, dt_bf, uT_bf, dt_w + (size_t)L * DINNER * DTRANK,
        dt_b + (size_t)L * DINNER, D_skip + (size_t)L * DINNER, qT, eT);
    k_scan<<<BATCH * (DINNER / 4), 256, 0, stream>>>(
        qT, eT, Bp, Cp, A_log + (size_t)L * DINNER * DSTATE, yT_bf);
    k_t2b<<<dim3(TLEN / 64, DINNER / 64, BATCH), 256, 0, stream>>>(yT_bf, y_bf);
    k_mm_g<<<dim3(3, NTOK / 128), 256, 0, stream>>>(y_bf, w_ou, h, h, DMODEL, DINNER);
  }

  k_head<<<NTOK / 4, 256, 0, stream>>>(h, head_w, head_b, out);
}

// Round 12
// 3721.534 us; speedup vs baseline: 1.7738x; 1.7738x over previous
//
#include <hip/hip_runtime.h>
#include <math.h>

#define BATCH 16
#define TLEN 2048
#define NTOK (BATCH*TLEN)       // 32768
#define DMODEL 160
#define DINNER 320
#define DSTATE 64
#define DTRANK 10
#define XDBL 138                // DT_RANK + 2*D_STATE (logical)
#define DCONV 12
#define PREK 9
#define NBLK 8
#define WPL 197760              // bf16 weights per layer (in 102400 + xp 44160 + out 51200)

typedef __attribute__((ext_vector_type(8))) short short8;
typedef __attribute__((ext_vector_type(4))) float floatx4;

__device__ __forceinline__ float sigmoidf_(float x) { return 1.f / (1.f + __expf(-x)); }
__device__ __forceinline__ unsigned short f2bf(float f) {
  union { float f; unsigned u; } v; v.f = f;
  unsigned r = v.u + 0x7FFF + ((v.u >> 16) & 1);   // round-to-nearest-even
  return (unsigned short)(r >> 16);
}
__device__ __forceinline__ float bf2f(unsigned short s) {
  union { unsigned u; float f; } v; v.u = ((unsigned)s) << 16;
  return v.f;
}
__device__ __forceinline__ float bflo(unsigned u) {   // low short -> float (B)
  union { unsigned u; float f; } v; v.u = u << 16; return v.f;
}
__device__ __forceinline__ float bfhi(unsigned u) {   // high short -> float (C)
  union { unsigned u; float f; } v; v.u = u & 0xFFFF0000u; return v.f;
}

// ---------------- pre conv (k=9, same pad) + exact GELU ----------------
__global__ __launch_bounds__(256)
void k_preconv(const float* __restrict__ x, const float* __restrict__ w,
               const float* __restrict__ bias, float* __restrict__ h) {
  int gid = blockIdx.x * 256 + threadIdx.x;
  if (gid >= NTOK * DMODEL) return;
  int c = gid % DMODEL;
  int tok = gid / DMODEL;
  int b = tok / TLEN, t = tok % TLEN;
  const float* xb = x + (size_t)b * TLEN;
  float acc = bias[c];
#pragma unroll
  for (int k = 0; k < PREK; ++k) {
    int tp = t + k - PREK / 2;
    float xv = (tp >= 0 && tp < TLEN) ? xb[tp] : 0.f;
    acc = fmaf(w[c * PREK + k], xv, acc);
  }
  h[gid] = 0.5f * acc * (1.f + erff(acc * 0.70710678118654752440f));
}

// ---------------- ALL-layer weight cast to bf16 (hoisted; grid = NBLK x 773) ----------------
__global__ __launch_bounds__(256)
void k_cast(const float* __restrict__ iw, const float* __restrict__ xw,
            const float* __restrict__ ow, unsigned short* __restrict__ wbf) {
  int L = blockIdx.x / 773;
  int i = (blockIdx.x % 773) * 256 + threadIdx.x;
  unsigned short* wl = wbf + (size_t)L * WPL;
  if (i < 102400) wl[i] = f2bf(iw[(size_t)L * 102400 + i]);
  else if (i < 146560) wl[i] = f2bf(xw[(size_t)L * 44160 + i - 102400]);
  else if (i < WPL) wl[i] = f2bf(ow[(size_t)L * 51200 + i - 146560]);
}

// ---------------- LayerNorm over d=160 -> bf16 out ----------------
__global__ __launch_bounds__(256)
void k_ln(const float* __restrict__ h, const float* __restrict__ g,
          const float* __restrict__ bb, unsigned short* __restrict__ y) {
  int row = blockIdx.x * 4 + (threadIdx.x >> 6);
  int lane = threadIdx.x & 63;
  const float* hr = h + (size_t)row * DMODEL;
  float v0 = hr[lane], v1 = hr[lane + 64];
  float v2 = (lane < DMODEL - 128) ? hr[lane + 128] : 0.f;
  float s = v0 + v1 + v2;
  float sq = v0 * v0 + v1 * v1 + v2 * v2;
#pragma unroll
  for (int off = 32; off; off >>= 1) {
    s += __shfl_xor(s, off);
    sq += __shfl_xor(sq, off);
  }
  float mean = s * (1.f / DMODEL);
  float var = sq * (1.f / DMODEL) - mean * mean;
  float rstd = rsqrtf(var + 1e-5f);
  unsigned short* yr = y + (size_t)row * DMODEL;
  yr[lane] = f2bf((v0 - mean) * rstd * g[lane] + bb[lane]);
  yr[lane + 64] = f2bf((v1 - mean) * rstd * g[lane + 64] + bb[lane + 64]);
  if (lane < DMODEL - 128)
    yr[lane + 128] = f2bf((v2 - mean) * rstd * g[lane + 128] + bb[lane + 128]);
}

// ------- in_proj MFMA GEMM: A_bf[M,160] @ W_bf[640,160]^T -> x fp32, z bf16 -------
__global__ __launch_bounds__(256)
void k_mm_in(const unsigned short* __restrict__ A, const unsigned short* __restrict__ Wb,
             float* __restrict__ xout, unsigned short* __restrict__ zout) {
  __shared__ short As[128 * 40];
  __shared__ short Ws[128 * 40];
  int tid = threadIdx.x;
  int m0 = blockIdx.y * 128, n0 = blockIdx.x * 128;
  int w = tid >> 6, lane = tid & 63;
  int rm = (w >> 1) * 64, cn = (w & 1) * 64;
  int lm = lane & 15, quad = lane >> 4;
  int r = tid >> 1, seg = tid & 1;
  const unsigned short* pA = A + (size_t)(m0 + r) * DMODEL + seg * 16;
  const unsigned short* pW = Wb + (size_t)(n0 + r) * DMODEL + seg * 16;
  floatx4 acc[4][4];
#pragma unroll
  for (int i = 0; i < 4; ++i)
#pragma unroll
    for (int j = 0; j < 4; ++j)
      acc[i][j] = (floatx4){0.f, 0.f, 0.f, 0.f};
  for (int kt = 0; kt < 5; ++kt) {
    uint4 a0 = *(const uint4*)(pA + kt * 32);
    uint4 a1 = *(const uint4*)(pA + kt * 32 + 8);
    uint4 w0 = *(const uint4*)(pW + kt * 32);
    uint4 w1 = *(const uint4*)(pW + kt * 32 + 8);
    *(short8*)&As[r * 40 + seg * 16]     = *(short8*)&a0;
    *(short8*)&As[r * 40 + seg * 16 + 8] = *(short8*)&a1;
    *(short8*)&Ws[r * 40 + seg * 16]     = *(short8*)&w0;
    *(short8*)&Ws[r * 40 + seg * 16 + 8] = *(short8*)&w1;
    __syncthreads();
    short8 af[4], wf[4];
#pragma unroll
    for (int i = 0; i < 4; ++i)
      af[i] = *(short8*)&As[(rm + i * 16 + lm) * 40 + quad * 8];
#pragma unroll
    for (int j = 0; j < 4; ++j)
      wf[j] = *(short8*)&Ws[(cn + j * 16 + lm) * 40 + quad * 8];
#pragma unroll
    for (int i = 0; i < 4; ++i)
#pragma unroll
      for (int j = 0; j < 4; ++j)
        acc[i][j] = __builtin_amdgcn_mfma_f32_16x16x32_bf16(af[i], wf[j], acc[i][j], 0, 0, 0);
    __syncthreads();
  }
#pragma unroll
  for (int i = 0; i < 4; ++i)
#pragma unroll
    for (int reg = 0; reg < 4; ++reg) {
      int m = m0 + rm + i * 16 + quad * 4 + reg;
#pragma unroll
      for (int j = 0; j < 4; ++j) {
        int n = n0 + cn + j * 16 + lm;
        float v = acc[i][j][reg];
        if (n < DINNER) xout[(size_t)m * DINNER + n] = v;
        else zout[(size_t)m * DINNER + n - DINNER] = f2bf(v);
      }
    }
}

// ------- out_proj MFMA GEMM: A_bf[M,K] @ W_bf[N,K]^T (+resid) -> C fp32 [M,N] -------
__global__ __launch_bounds__(256)
void k_mm_g(const unsigned short* __restrict__ A, const unsigned short* __restrict__ Wb,
            float* __restrict__ C, const float* __restrict__ resid, int N, int K) {
  __shared__ short As[128 * 40];
  __shared__ short Ws[64 * 40];
  int tid = threadIdx.x;
  int m0 = blockIdx.y * 128, n0 = blockIdx.x * 64;
  int w = tid >> 6, lane = tid & 63;
  int rm = w * 32;
  int lm = lane & 15, quad = lane >> 4;
  int r = tid >> 1, seg = tid & 1;
  int wr = tid >> 2, wseg = tid & 3;
  bool wvld = (n0 + wr) < N;
  const unsigned short* pA = A + (size_t)(m0 + r) * K + seg * 16;
  const unsigned short* pW = Wb + (size_t)(wvld ? (n0 + wr) : 0) * K + wseg * 8;
  floatx4 acc[2][4];
#pragma unroll
  for (int i = 0; i < 2; ++i)
#pragma unroll
    for (int j = 0; j < 4; ++j)
      acc[i][j] = (floatx4){0.f, 0.f, 0.f, 0.f};
  int nk = K >> 5;
  for (int kt = 0; kt < nk; ++kt) {
    uint4 a0 = *(const uint4*)(pA + kt * 32);
    uint4 a1 = *(const uint4*)(pA + kt * 32 + 8);
    uint4 wv = wvld ? *(const uint4*)(pW + kt * 32)
                    : make_uint4(0u, 0u, 0u, 0u);
    *(short8*)&As[r * 40 + seg * 16]     = *(short8*)&a0;
    *(short8*)&As[r * 40 + seg * 16 + 8] = *(short8*)&a1;
    *(short8*)&Ws[wr * 40 + wseg * 8]    = *(short8*)&wv;
    __syncthreads();
    short8 af[2], wf[4];
#pragma unroll
    for (int i = 0; i < 2; ++i)
      af[i] = *(short8*)&As[(rm + i * 16 + lm) * 40 + quad * 8];
#pragma unroll
    for (int j = 0; j < 4; ++j)
      wf[j] = *(short8*)&Ws[(j * 16 + lm) * 40 + quad * 8];
#pragma unroll
    for (int i = 0; i < 2; ++i)
#pragma unroll
      for (int j = 0; j < 4; ++j)
        acc[i][j] = __builtin_amdgcn_mfma_f32_16x16x32_bf16(af[i], wf[j], acc[i][j], 0, 0, 0);
    __syncthreads();
  }
#pragma unroll
  for (int i = 0; i < 2; ++i)
#pragma unroll
    for (int reg = 0; reg < 4; ++reg) {
      int m = m0 + rm + i * 16 + quad * 4 + reg;
#pragma unroll
      for (int j = 0; j < 4; ++j) {
        int n = n0 + j * 16 + lm;
        if (n < N) {
          float v = acc[i][j][reg];
          if (resid) v += resid[(size_t)m * N + n];
          C[(size_t)m * N + n] = v;
        }
      }
    }
}

// ------- xproj MFMA GEMM -> dt_bf[tok][12] bf16 + bcP[tok][64] packed (B lo | C hi) -------
__global__ __launch_bounds__(256)
void k_mm_x(const unsigned short* __restrict__ A, const unsigned short* __restrict__ Wb,
            unsigned short* __restrict__ dtb, unsigned short* __restrict__ bcP) {
  const int N = XDBL, K = DINNER;
  __shared__ short As[128 * 40];
  __shared__ short Ws[64 * 40];
  int tid = threadIdx.x;
  int m0 = blockIdx.y * 128, n0 = blockIdx.x * 64;
  int w = tid >> 6, lane = tid & 63;
  int rm = w * 32;
  int lm = lane & 15, quad = lane >> 4;
  int r = tid >> 1, seg = tid & 1;
  int wr = tid >> 2, wseg = tid & 3;
  bool wvld = (n0 + wr) < N;
  const unsigned short* pA = A + (size_t)(m0 + r) * K + seg * 16;
  const unsigned short* pW = Wb + (size_t)(wvld ? (n0 + wr) : 0) * K + wseg * 8;
  floatx4 acc[2][4];
#pragma unroll
  for (int i = 0; i < 2; ++i)
#pragma unroll
    for (int j = 0; j < 4; ++j)
      acc[i][j] = (floatx4){0.f, 0.f, 0.f, 0.f};
  int nk = K >> 5;
  for (int kt = 0; kt < nk; ++kt) {
    uint4 a0 = *(const uint4*)(pA + kt * 32);
    uint4 a1 = *(const uint4*)(pA + kt * 32 + 8);
    uint4 wv = wvld ? *(const uint4*)(pW + kt * 32)
                    : make_uint4(0u, 0u, 0u, 0u);
    *(short8*)&As[r * 40 + seg * 16]     = *(short8*)&a0;
    *(short8*)&As[r * 40 + seg * 16 + 8] = *(short8*)&a1;
    *(short8*)&Ws[wr * 40 + wseg * 8]    = *(short8*)&wv;
    __syncthreads();
    short8 af[2], wf[4];
#pragma unroll
    for (int i = 0; i < 2; ++i)
      af[i] = *(short8*)&As[(rm + i * 16 + lm) * 40 + quad * 8];
#pragma unroll
    for (int j = 0; j < 4; ++j)
      wf[j] = *(short8*)&Ws[(j * 16 + lm) * 40 + quad * 8];
#pragma unroll
    for (int i = 0; i < 2; ++i)
#pragma unroll
      for (int j = 0; j < 4; ++j)
        acc[i][j] = __builtin_amdgcn_mfma_f32_16x16x32_bf16(af[i], wf[j], acc[i][j], 0, 0, 0);
    __syncthreads();
  }
#pragma unroll
  for (int i = 0; i < 2; ++i)
#pragma unroll
    for (int reg = 0; reg < 4; ++reg) {
      int m = m0 + rm + i * 16 + quad * 4 + reg;
#pragma unroll
      for (int j = 0; j < 4; ++j) {
        int n = n0 + j * 16 + lm;
        if (n < N) {
          float v = acc[i][j][reg];
          if (n < DTRANK) dtb[(size_t)m * 12 + n] = f2bf(v);
          else if (n < DTRANK + DSTATE)
            bcP[(size_t)m * 128 + 2 * (n - DTRANK)] = f2bf(v);        // B -> low short
          else
            bcP[(size_t)m * 128 + 2 * (n - DTRANK - DSTATE) + 1] = f2bf(v); // C -> high short
        }
      }
    }
}

// ---- depthwise causal conv (k=12) + SiLU: xbuf[tok][d] -> u_bf token-major + uT_bf time-major ----
__global__ __launch_bounds__(256)
void k_convT(const float* __restrict__ xbuf, const float* __restrict__ cw,
             const float* __restrict__ cb, unsigned short* __restrict__ uTb,
             unsigned short* __restrict__ ubf) {
  int t0 = blockIdx.x * 64, d0 = blockIdx.y * 64, b = blockIdx.z;
  __shared__ float xs[76 * 65];
  __shared__ float us[64 * 65];
  int tid = threadIdx.x, j = tid & 63, w = tid >> 6;
#pragma unroll
  for (int it = 0; it < 19; ++it) {
    int r = it * 4 + w;
    int t = t0 - (DCONV - 1) + r;
    xs[r * 65 + j] = (t >= 0 && t < TLEN)
        ? xbuf[((size_t)b * TLEN + t) * DINNER + d0 + j] : 0.f;
  }
  __syncthreads();
  float cwr[DCONV];
#pragma unroll
  for (int k = 0; k < DCONV; ++k) cwr[k] = cw[(d0 + j) * DCONV + k];
  float cbv = cb[d0 + j];
#pragma unroll
  for (int it = 0; it < 16; ++it) {
    int tl = it * 4 + w;
    float acc = cbv;
#pragma unroll
    for (int k = 0; k < DCONV; ++k)
      acc = fmaf(cwr[k], xs[(tl + k) * 65 + j], acc);
    us[tl * 65 + j] = acc * sigmoidf_(acc);
  }
  __syncthreads();
#pragma unroll
  for (int it = 0; it < 16; ++it) {
    int tr = it * 4 + w;
    ubf[((size_t)b * TLEN + t0 + tr) * DINNER + d0 + j] = f2bf(us[tr * 65 + j]);
  }
#pragma unroll
  for (int it = 0; it < 16; ++it) {
    int dl = it * 4 + w;
    uTb[((size_t)b * DINNER + d0 + dl) * TLEN + t0 + j] = f2bf(us[j * 65 + dl]);
  }
}

// ---- pack: qT = {del, del*u} float2 time-major; eT = {skip | ssz<<16} uint ----
__global__ __launch_bounds__(256)
void k_pack(const unsigned short* __restrict__ zbuf, const unsigned short* __restrict__ dtbf,
            const unsigned short* __restrict__ uTb,
            const float* __restrict__ dtw, const float* __restrict__ dtb,
            const float* __restrict__ Dskip,
            float2* __restrict__ qT, unsigned* __restrict__ eT) {
  int t0 = blockIdx.x * 64, d0 = blockIdx.y * 64, b = blockIdx.z;
  __shared__ float zs[64 * 65];
  __shared__ float xd[64 * 13];
  int tid = threadIdx.x, j = tid & 63, w = tid >> 6;
#pragma unroll
  for (int it = 0; it < 16; ++it) {
    int i = it * 4 + w;
    zs[i * 65 + j] = bf2f(zbuf[((size_t)b * TLEN + t0 + i) * DINNER + d0 + j]);
  }
  {
    int r = tid >> 2, c = tid & 3;
    size_t rowb = ((size_t)b * TLEN + t0 + r) * 12;
    for (int cc = c; cc < DTRANK; cc += 4)
      xd[r * 13 + cc] = bf2f(dtbf[rowb + cc]);
  }
  __syncthreads();
#pragma unroll
  for (int it = 0; it < 16; ++it) {
    int dl = it * 4 + w, d = d0 + dl;
    float acc = dtb[d];
    const float* wr = dtw + d * DTRANK;
#pragma unroll
    for (int rr = 0; rr < DTRANK; ++rr)
      acc = fmaf(xd[j * 13 + rr], wr[rr], acc);
    float del = (acc > 20.f) ? acc : log1pf(__expf(acc));
    size_t o = ((size_t)b * DINNER + d) * TLEN + t0 + j;
    float uv = bf2f(uTb[o]);
    float zv = zs[j * 65 + dl];
    float ssz = zv * sigmoidf_(zv);
    qT[o] = make_float2(del, del * uv);
    unsigned lo = f2bf(uv * Dskip[d] * ssz);
    unsigned hi = f2bf(ssz);
    eT[o] = lo | (hi << 16);
  }
}

// ---------------- selective scan: wave per (b,d), lane = state; no barriers ----------------
// Per t: b64 q broadcast + 1 coalesced packed-bc dword (stride 256B -> all-immediate offsets).
__global__ __launch_bounds__(256)
void k_scan(const float2* __restrict__ qT, const unsigned* __restrict__ eT,
            const unsigned* __restrict__ bcP, const float* __restrict__ Alog,
            unsigned short* __restrict__ yTb) {
  int wave = threadIdx.x >> 6, lane = threadIdx.x & 63;
  int b = blockIdx.x / (DINNER / 4);
  int d = (blockIdx.x % (DINNER / 4)) * 4 + wave;
  __shared__ float ps_all[4][16 * 68];
  float* ps = ps_all[wave];               // per-wave region; same-wave DS ops are ordered
  float Al2 = -__expf(Alog[d * DSTATE + lane]) * 1.44269504088896340736f;
  size_t chan = ((size_t)b * DINNER + d) * TLEN;
  const float2* pq = qT + chan;
  const unsigned* pe = eT + chan;
  unsigned short* py = yTb + chan;
  const unsigned* xb = bcP + (size_t)b * TLEN * DSTATE + lane;
  float h = 0.f;
  int tl = lane & 15, qq = lane >> 4;
  for (int t0 = 0; t0 < TLEN; t0 += 16) {
#pragma unroll
    for (int t = 0; t < 16; ++t) {
      float2 q = pq[t0 + t];
      unsigned bc = xb[(size_t)(t0 + t) * DSTATE];
      float Bv = bflo(bc), Cv = bfhi(bc);
      h = fmaf(h, exp2f(q.x * Al2), q.y * Bv);
      ps[t * 68 + lane] = h * Cv;
    }
    float p = 0.f;
    const floatx4* pr = (const floatx4*)&ps[tl * 68 + qq * 16];
#pragma unroll
    for (int i = 0; i < 4; ++i) {
      floatx4 v = pr[i];
      p += v[0] + v[1] + v[2] + v[3];
    }
    p += __shfl_xor(p, 16);
    p += __shfl_xor(p, 32);
    if (lane < 16) {
      int t = t0 + tl;
      unsigned e = pe[t];
      py[t] = f2bf(fmaf(p, bfhi(e), bflo(e)));
    }
  }
}

// ---- transpose yT_bf[b][d][t] -> y_bf[tok][d] (bf16 -> bf16) ----
__global__ __launch_bounds__(256)
void k_t2b(const unsigned short* __restrict__ yTb, unsigned short* __restrict__ ybf) {
  int t0 = blockIdx.x * 64, d0 = blockIdx.y * 64, b = blockIdx.z;
  __shared__ unsigned short ls[64 * 66];
  int tid = threadIdx.x, j = tid & 63, w = tid >> 6;
#pragma unroll
  for (int it = 0; it < 16; ++it) {
    int dl = it * 4 + w;
    ls[dl * 66 + j] = yTb[((size_t)b * DINNER + d0 + dl) * TLEN + t0 + j];
  }
  __syncthreads();
#pragma unroll
  for (int it = 0; it < 16; ++it) {
    int tr = it * 4 + w;
    ybf[((size_t)b * TLEN + t0 + tr) * DINNER + d0 + j] = ls[j * 66 + tr];
  }
}

// ---------------- head ----------------
__global__ __launch_bounds__(256)
void k_head(const float* __restrict__ h, const float* __restrict__ hw,
            const float* __restrict__ hb, float* __restrict__ out) {
  int tok = blockIdx.x * 4 + (threadIdx.x >> 6);
  int lane = threadIdx.x & 63;
  const float* hr = h + (size_t)tok * DMODEL;
  float s = hr[lane] * hw[lane] + hr[lane + 64] * hw[lane + 64];
  if (lane < DMODEL - 128) s += hr[lane + 128] * hw[lane + 128];
#pragma unroll
  for (int off = 32; off; off >>= 1) s += __shfl_xor(s, off);
  if (lane == 0) out[tok] = s + hb[0];
}

extern "C" void kernel_launch(void* const* d_in, const int* in_sizes, int n_in,
                              void* d_out, int out_size, void* d_ws, size_t ws_size,
                              hipStream_t stream) {
  const float* x      = (const float*)d_in[0];
  const float* pre_w  = (const float*)d_in[1];
  const float* pre_b  = (const float*)d_in[2];
  const float* ln_g   = (const float*)d_in[3];
  const float* ln_b   = (const float*)d_in[4];
  const float* in_w   = (const float*)d_in[5];
  const float* conv_w = (const float*)d_in[6];
  const float* conv_b = (const float*)d_in[7];
  const float* xproj_w= (const float*)d_in[8];
  const float* dt_w   = (const float*)d_in[9];
  const float* dt_b   = (const float*)d_in[10];
  const float* A_log  = (const float*)d_in[11];
  const float* D_skip = (const float*)d_in[12];
  const float* out_w  = (const float*)d_in[13];
  const float* head_w = (const float*)d_in[14];
  const float* head_b = (const float*)d_in[15];
  float* out = (float*)d_out;

  // workspace (float units), total ~50.3M f = 201 MB (< proven 209.7):
  // h | bcP (dword/t/state) | dt_bf | qT (also lnxd_bf/u_bf before pack) | uT_bf |
  // X (xbuf fp32 -> eT -> y_bf) | Y (zbuf_bf -> yT_bf) | wbf (all layers)
  float* ws = (float*)d_ws;
  float* h    = ws;
  unsigned* bcP = (unsigned*)(h + (size_t)NTOK * DMODEL);
  unsigned short* dt_bf = (unsigned short*)(bcP + (size_t)NTOK * DSTATE);
  float2* qT  = (float2*)(dt_bf + (size_t)NTOK * 12);
  unsigned short* uT_bf = (unsigned short*)(qT + (size_t)NTOK * DINNER);
  float* X    = (float*)(uT_bf + (size_t)NTOK * DINNER);
  float* Y    = X + (size_t)NTOK * DINNER;
  unsigned short* wbf = (unsigned short*)(Y + (size_t)NTOK * DINNER / 2);

  unsigned short* lnxd_bf = (unsigned short*)qT;   // dead before pack writes qT
  unsigned short* u_bf    = (unsigned short*)qT;   // dead before pack writes qT
  float*          xbuf    = X;
  unsigned*       eT      = (unsigned*)X;          // xbuf dead after convT
  unsigned short* y_bf    = (unsigned short*)X;    // eT dead after scan
  unsigned short* zbuf_bf = (unsigned short*)Y;
  unsigned short* yT_bf   = (unsigned short*)Y;    // zbuf dead after pack

  k_preconv<<<NTOK * DMODEL / 256, 256, 0, stream>>>(x, pre_w, pre_b, h);
  k_cast<<<NBLK * 773, 256, 0, stream>>>(in_w, xproj_w, out_w, wbf);

  for (int L = 0; L < NBLK; ++L) {
    unsigned short* w_in = wbf + (size_t)L * WPL;
    unsigned short* w_xp = w_in + 102400;
    unsigned short* w_ou = w_in + 146560;
    k_ln<<<NTOK / 4, 256, 0, stream>>>(h, ln_g + L * DMODEL, ln_b + L * DMODEL, lnxd_bf);
    k_mm_in<<<dim3(5, NTOK / 128), 256, 0, stream>>>(lnxd_bf, w_in, xbuf, zbuf_bf);
    k_convT<<<dim3(TLEN / 64, DINNER / 64, BATCH), 256, 0, stream>>>(
        xbuf, conv_w + (size_t)L * DINNER * DCONV, conv_b + (size_t)L * DINNER,
        uT_bf, u_bf);
    k_mm_x<<<dim3(3, NTOK / 128), 256, 0, stream>>>(u_bf, w_xp, dt_bf,
                                                    (unsigned short*)bcP);
    k_pack<<<dim3(TLEN / 64, DINNER / 64, BATCH), 256, 0, stream>>>(
        zbuf_bf, dt_bf, uT_bf, dt_w + (size_t)L * DINNER * DTRANK,
        dt_b + (size_t)L * DINNER, D_skip + (size_t)L * DINNER, qT, eT);
    k_scan<<<BATCH * (DINNER / 4), 256, 0, stream>>>(
        qT, eT, bcP, A_log + (size_t)L * DINNER * DSTATE, yT_bf);
    k_t2b<<<dim3(TLEN / 64, DINNER / 64, BATCH), 256, 0, stream>>>(yT_bf, y_bf);
    k_mm_g<<<dim3(3, NTOK / 128), 256, 0, stream>>>(y_bf, w_ou, h, h, DMODEL, DINNER);
  }

  k_head<<<NTOK / 4, 256, 0, stream>>>(h, head_w, head_b, out);
}

// Round 13
// 3609.577 us; speedup vs baseline: 1.8288x; 1.0310x over previous
//
#include <hip/hip_runtime.h>
#include <math.h>

#define BATCH 16
#define TLEN 2048
#define NTOK (BATCH*TLEN)       // 32768
#define DMODEL 160
#define DINNER 320
#define DSTATE 64
#define DTRANK 10
#define XDBL 138                // DT_RANK + 2*D_STATE (logical)
#define XP 140                  // padded interleaved row: 10 dt + 2 pad + 64 (B,C) pairs
#define DCONV 12
#define PREK 9
#define NBLK 8
#define WPL 197760              // bf16 weights per layer (in 102400 + xp 44160 + out 51200)

typedef __attribute__((ext_vector_type(8))) short short8;
typedef __attribute__((ext_vector_type(4))) float floatx4;

__device__ __forceinline__ float sigmoidf_(float x) { return 1.f / (1.f + __expf(-x)); }
__device__ __forceinline__ unsigned short f2bf(float f) {
  union { float f; unsigned u; } v; v.f = f;
  unsigned r = v.u + 0x7FFF + ((v.u >> 16) & 1);   // round-to-nearest-even
  return (unsigned short)(r >> 16);
}
__device__ __forceinline__ float bf2f(unsigned short s) {
  union { unsigned u; float f; } v; v.u = ((unsigned)s) << 16;
  return v.f;
}
__device__ __forceinline__ float bflo(unsigned u) {   // low short -> float
  union { unsigned u; float f; } v; v.u = u << 16; return v.f;
}
__device__ __forceinline__ float bfhi(unsigned u) {   // high short -> float
  union { unsigned u; float f; } v; v.u = u & 0xFFFF0000u; return v.f;
}

// ---------------- pre conv (k=9, same pad) + exact GELU ----------------
__global__ __launch_bounds__(256)
void k_preconv(const float* __restrict__ x, const float* __restrict__ w,
               const float* __restrict__ bias, float* __restrict__ h) {
  int gid = blockIdx.x * 256 + threadIdx.x;
  if (gid >= NTOK * DMODEL) return;
  int c = gid % DMODEL;
  int tok = gid / DMODEL;
  int b = tok / TLEN, t = tok % TLEN;
  const float* xb = x + (size_t)b * TLEN;
  float acc = bias[c];
#pragma unroll
  for (int k = 0; k < PREK; ++k) {
    int tp = t + k - PREK / 2;
    float xv = (tp >= 0 && tp < TLEN) ? xb[tp] : 0.f;
    acc = fmaf(w[c * PREK + k], xv, acc);
  }
  h[gid] = 0.5f * acc * (1.f + erff(acc * 0.70710678118654752440f));
}

// ---------------- ALL-layer weight cast to bf16 (hoisted; grid = NBLK x 773) ----------------
__global__ __launch_bounds__(256)
void k_cast(const float* __restrict__ iw, const float* __restrict__ xw,
            const float* __restrict__ ow, unsigned short* __restrict__ wbf) {
  int L = blockIdx.x / 773;
  int i = (blockIdx.x % 773) * 256 + threadIdx.x;
  unsigned short* wl = wbf + (size_t)L * WPL;
  if (i < 102400) wl[i] = f2bf(iw[(size_t)L * 102400 + i]);
  else if (i < 146560) wl[i] = f2bf(xw[(size_t)L * 44160 + i - 102400]);
  else if (i < WPL) wl[i] = f2bf(ow[(size_t)L * 51200 + i - 146560]);
}

// ---------------- LayerNorm over d=160 -> bf16 out ----------------
__global__ __launch_bounds__(256)
void k_ln(const float* __restrict__ h, const float* __restrict__ g,
          const float* __restrict__ bb, unsigned short* __restrict__ y) {
  int row = blockIdx.x * 4 + (threadIdx.x >> 6);
  int lane = threadIdx.x & 63;
  const float* hr = h + (size_t)row * DMODEL;
  float v0 = hr[lane], v1 = hr[lane + 64];
  float v2 = (lane < DMODEL - 128) ? hr[lane + 128] : 0.f;
  float s = v0 + v1 + v2;
  float sq = v0 * v0 + v1 * v1 + v2 * v2;
#pragma unroll
  for (int off = 32; off; off >>= 1) {
    s += __shfl_xor(s, off);
    sq += __shfl_xor(sq, off);
  }
  float mean = s * (1.f / DMODEL);
  float var = sq * (1.f / DMODEL) - mean * mean;
  float rstd = rsqrtf(var + 1e-5f);
  unsigned short* yr = y + (size_t)row * DMODEL;
  yr[lane] = f2bf((v0 - mean) * rstd * g[lane] + bb[lane]);
  yr[lane + 64] = f2bf((v1 - mean) * rstd * g[lane + 64] + bb[lane + 64]);
  if (lane < DMODEL - 128)
    yr[lane + 128] = f2bf((v2 - mean) * rstd * g[lane + 128] + bb[lane + 128]);
}

// ------- in_proj MFMA GEMM: A_bf[M,160] @ W_bf[640,160]^T -> x fp32, z bf16 -------
__global__ __launch_bounds__(256)
void k_mm_in(const unsigned short* __restrict__ A, const unsigned short* __restrict__ Wb,
             float* __restrict__ xout, unsigned short* __restrict__ zout) {
  __shared__ short As[128 * 40];
  __shared__ short Ws[128 * 40];
  int tid = threadIdx.x;
  int m0 = blockIdx.y * 128, n0 = blockIdx.x * 128;
  int w = tid >> 6, lane = tid & 63;
  int rm = (w >> 1) * 64, cn = (w & 1) * 64;
  int lm = lane & 15, quad = lane >> 4;
  int r = tid >> 1, seg = tid & 1;
  const unsigned short* pA = A + (size_t)(m0 + r) * DMODEL + seg * 16;
  const unsigned short* pW = Wb + (size_t)(n0 + r) * DMODEL + seg * 16;
  floatx4 acc[4][4];
#pragma unroll
  for (int i = 0; i < 4; ++i)
#pragma unroll
    for (int j = 0; j < 4; ++j)
      acc[i][j] = (floatx4){0.f, 0.f, 0.f, 0.f};
  for (int kt = 0; kt < 5; ++kt) {
    uint4 a0 = *(const uint4*)(pA + kt * 32);
    uint4 a1 = *(const uint4*)(pA + kt * 32 + 8);
    uint4 w0 = *(const uint4*)(pW + kt * 32);
    uint4 w1 = *(const uint4*)(pW + kt * 32 + 8);
    *(short8*)&As[r * 40 + seg * 16]     = *(short8*)&a0;
    *(short8*)&As[r * 40 + seg * 16 + 8] = *(short8*)&a1;
    *(short8*)&Ws[r * 40 + seg * 16]     = *(short8*)&w0;
    *(short8*)&Ws[r * 40 + seg * 16 + 8] = *(short8*)&w1;
    __syncthreads();
    short8 af[4], wf[4];
#pragma unroll
    for (int i = 0; i < 4; ++i)
      af[i] = *(short8*)&As[(rm + i * 16 + lm) * 40 + quad * 8];
#pragma unroll
    for (int j = 0; j < 4; ++j)
      wf[j] = *(short8*)&Ws[(cn + j * 16 + lm) * 40 + quad * 8];
#pragma unroll
    for (int i = 0; i < 4; ++i)
#pragma unroll
      for (int j = 0; j < 4; ++j)
        acc[i][j] = __builtin_amdgcn_mfma_f32_16x16x32_bf16(af[i], wf[j], acc[i][j], 0, 0, 0);
    __syncthreads();
  }
#pragma unroll
  for (int i = 0; i < 4; ++i)
#pragma unroll
    for (int reg = 0; reg < 4; ++reg) {
      int m = m0 + rm + i * 16 + quad * 4 + reg;
#pragma unroll
      for (int j = 0; j < 4; ++j) {
        int n = n0 + cn + j * 16 + lm;
        float v = acc[i][j][reg];
        if (n < DINNER) xout[(size_t)m * DINNER + n] = v;
        else zout[(size_t)m * DINNER + n - DINNER] = f2bf(v);
      }
    }
}

// ------- out_proj MFMA GEMM: A_bf[M,K] @ W_bf[N,K]^T (+resid) -> C fp32 [M,N] -------
__global__ __launch_bounds__(256)
void k_mm_g(const unsigned short* __restrict__ A, const unsigned short* __restrict__ Wb,
            float* __restrict__ C, const float* __restrict__ resid, int N, int K) {
  __shared__ short As[128 * 40];
  __shared__ short Ws[64 * 40];
  int tid = threadIdx.x;
  int m0 = blockIdx.y * 128, n0 = blockIdx.x * 64;
  int w = tid >> 6, lane = tid & 63;
  int rm = w * 32;
  int lm = lane & 15, quad = lane >> 4;
  int r = tid >> 1, seg = tid & 1;
  int wr = tid >> 2, wseg = tid & 3;
  bool wvld = (n0 + wr) < N;
  const unsigned short* pA = A + (size_t)(m0 + r) * K + seg * 16;
  const unsigned short* pW = Wb + (size_t)(wvld ? (n0 + wr) : 0) * K + wseg * 8;
  floatx4 acc[2][4];
#pragma unroll
  for (int i = 0; i < 2; ++i)
#pragma unroll
    for (int j = 0; j < 4; ++j)
      acc[i][j] = (floatx4){0.f, 0.f, 0.f, 0.f};
  int nk = K >> 5;
  for (int kt = 0; kt < nk; ++kt) {
    uint4 a0 = *(const uint4*)(pA + kt * 32);
    uint4 a1 = *(const uint4*)(pA + kt * 32 + 8);
    uint4 wv = wvld ? *(const uint4*)(pW + kt * 32)
                    : make_uint4(0u, 0u, 0u, 0u);
    *(short8*)&As[r * 40 + seg * 16]     = *(short8*)&a0;
    *(short8*)&As[r * 40 + seg * 16 + 8] = *(short8*)&a1;
    *(short8*)&Ws[wr * 40 + wseg * 8]    = *(short8*)&wv;
    __syncthreads();
    short8 af[2], wf[4];
#pragma unroll
    for (int i = 0; i < 2; ++i)
      af[i] = *(short8*)&As[(rm + i * 16 + lm) * 40 + quad * 8];
#pragma unroll
    for (int j = 0; j < 4; ++j)
      wf[j] = *(short8*)&Ws[(j * 16 + lm) * 40 + quad * 8];
#pragma unroll
    for (int i = 0; i < 2; ++i)
#pragma unroll
      for (int j = 0; j < 4; ++j)
        acc[i][j] = __builtin_amdgcn_mfma_f32_16x16x32_bf16(af[i], wf[j], acc[i][j], 0, 0, 0);
    __syncthreads();
  }
#pragma unroll
  for (int i = 0; i < 2; ++i)
#pragma unroll
    for (int reg = 0; reg < 4; ++reg) {
      int m = m0 + rm + i * 16 + quad * 4 + reg;
#pragma unroll
      for (int j = 0; j < 4; ++j) {
        int n = n0 + j * 16 + lm;
        if (n < N) {
          float v = acc[i][j][reg];
          if (resid) v += resid[(size_t)m * N + n];
          C[(size_t)m * N + n] = v;
        }
      }
    }
}

// ------- xproj MFMA GEMM -> interleaved bf16 rows [M][XP]: dt(10)+pad(2)+ (B_s,C_s) pairs -------
__global__ __launch_bounds__(256)
void k_mm_x(const unsigned short* __restrict__ A, const unsigned short* __restrict__ Wb,
            unsigned short* __restrict__ C) {
  const int N = XDBL, K = DINNER;
  __shared__ short As[128 * 40];
  __shared__ short Ws[64 * 40];
  int tid = threadIdx.x;
  int m0 = blockIdx.y * 128, n0 = blockIdx.x * 64;
  int w = tid >> 6, lane = tid & 63;
  int rm = w * 32;
  int lm = lane & 15, quad = lane >> 4;
  int r = tid >> 1, seg = tid & 1;
  int wr = tid >> 2, wseg = tid & 3;
  bool wvld = (n0 + wr) < N;
  const unsigned short* pA = A + (size_t)(m0 + r) * K + seg * 16;
  const unsigned short* pW = Wb + (size_t)(wvld ? (n0 + wr) : 0) * K + wseg * 8;
  floatx4 acc[2][4];
#pragma unroll
  for (int i = 0; i < 2; ++i)
#pragma unroll
    for (int j = 0; j < 4; ++j)
      acc[i][j] = (floatx4){0.f, 0.f, 0.f, 0.f};
  int nk = K >> 5;
  for (int kt = 0; kt < nk; ++kt) {
    uint4 a0 = *(const uint4*)(pA + kt * 32);
    uint4 a1 = *(const uint4*)(pA + kt * 32 + 8);
    uint4 wv = wvld ? *(const uint4*)(pW + kt * 32)
                    : make_uint4(0u, 0u, 0u, 0u);
    *(short8*)&As[r * 40 + seg * 16]     = *(short8*)&a0;
    *(short8*)&As[r * 40 + seg * 16 + 8] = *(short8*)&a1;
    *(short8*)&Ws[wr * 40 + wseg * 8]    = *(short8*)&wv;
    __syncthreads();
    short8 af[2], wf[4];
#pragma unroll
    for (int i = 0; i < 2; ++i)
      af[i] = *(short8*)&As[(rm + i * 16 + lm) * 40 + quad * 8];
#pragma unroll
    for (int j = 0; j < 4; ++j)
      wf[j] = *(short8*)&Ws[(j * 16 + lm) * 40 + quad * 8];
#pragma unroll
    for (int i = 0; i < 2; ++i)
#pragma unroll
      for (int j = 0; j < 4; ++j)
        acc[i][j] = __builtin_amdgcn_mfma_f32_16x16x32_bf16(af[i], wf[j], acc[i][j], 0, 0, 0);
    __syncthreads();
  }
#pragma unroll
  for (int i = 0; i < 2; ++i)
#pragma unroll
    for (int reg = 0; reg < 4; ++reg) {
      int m = m0 + rm + i * 16 + quad * 4 + reg;
#pragma unroll
      for (int j = 0; j < 4; ++j) {
        int n = n0 + j * 16 + lm;
        if (n < N) {
          int slot = (n < DTRANK) ? n
                   : (n < DTRANK + DSTATE) ? 12 + 2 * (n - DTRANK)
                                           : 13 + 2 * (n - DTRANK - DSTATE);
          C[(size_t)m * XP + slot] = f2bf(acc[i][j][reg]);
        }
      }
    }
}

// ---- depthwise causal conv (k=12) + SiLU: xbuf[tok][d] -> u_bf token-major + uT_bf time-major ----
__global__ __launch_bounds__(256)
void k_convT(const float* __restrict__ xbuf, const float* __restrict__ cw,
             const float* __restrict__ cb, unsigned short* __restrict__ uTb,
             unsigned short* __restrict__ ubf) {
  int t0 = blockIdx.x * 64, d0 = blockIdx.y * 64, b = blockIdx.z;
  __shared__ float xs[76 * 65];
  __shared__ float us[64 * 65];
  int tid = threadIdx.x, j = tid & 63, w = tid >> 6;
#pragma unroll
  for (int it = 0; it < 19; ++it) {
    int r = it * 4 + w;                 // 0..75
    int t = t0 - (DCONV - 1) + r;
    xs[r * 65 + j] = (t >= 0 && t < TLEN)
        ? xbuf[((size_t)b * TLEN + t) * DINNER + d0 + j] : 0.f;
  }
  __syncthreads();
  float cwr[DCONV];
#pragma unroll
  for (int k = 0; k < DCONV; ++k) cwr[k] = cw[(d0 + j) * DCONV + k];
  float cbv = cb[d0 + j];
#pragma unroll
  for (int it = 0; it < 16; ++it) {
    int tl = it * 4 + w;                // 0..63
    float acc = cbv;
#pragma unroll
    for (int k = 0; k < DCONV; ++k)
      acc = fmaf(cwr[k], xs[(tl + k) * 65 + j], acc);
    us[tl * 65 + j] = acc * sigmoidf_(acc);
  }
  __syncthreads();
#pragma unroll
  for (int it = 0; it < 16; ++it) {
    int tr = it * 4 + w;
    ubf[((size_t)b * TLEN + t0 + tr) * DINNER + d0 + j] = f2bf(us[tr * 65 + j]);
  }
#pragma unroll
  for (int it = 0; it < 16; ++it) {
    int dl = it * 4 + w;
    uTb[((size_t)b * DINNER + d0 + dl) * TLEN + t0 + j] = f2bf(us[j * 65 + dl]);
  }
}

// ---- pack: qT = {del, del*u} float2 time-major; eT = {skip=u*D*ssz | ssz<<16} uint ----
__global__ __launch_bounds__(256)
void k_pack(const unsigned short* __restrict__ zbuf, const unsigned short* __restrict__ xdbl,
            const unsigned short* __restrict__ uTb,
            const float* __restrict__ dtw, const float* __restrict__ dtb,
            const float* __restrict__ Dskip,
            float2* __restrict__ qT, unsigned* __restrict__ eT) {
  int t0 = blockIdx.x * 64, d0 = blockIdx.y * 64, b = blockIdx.z;
  __shared__ float zs[64 * 65];
  __shared__ float xd[64 * 13];
  int tid = threadIdx.x, j = tid & 63, w = tid >> 6;
#pragma unroll
  for (int it = 0; it < 16; ++it) {
    int i = it * 4 + w;
    zs[i * 65 + j] = bf2f(zbuf[((size_t)b * TLEN + t0 + i) * DINNER + d0 + j]);
  }
  {
    int r = tid >> 2, c = tid & 3;
    size_t rowb = ((size_t)b * TLEN + t0 + r) * XP;
    for (int cc = c; cc < DTRANK; cc += 4)
      xd[r * 13 + cc] = bf2f(xdbl[rowb + cc]);
  }
  __syncthreads();
#pragma unroll
  for (int it = 0; it < 16; ++it) {
    int dl = it * 4 + w, d = d0 + dl;
    float acc = dtb[d];
    const float* wr = dtw + d * DTRANK;
#pragma unroll
    for (int rr = 0; rr < DTRANK; ++rr)
      acc = fmaf(xd[j * 13 + rr], wr[rr], acc);
    float del = (acc > 20.f) ? acc : log1pf(__expf(acc));
    size_t o = ((size_t)b * DINNER + d) * TLEN + t0 + j;
    float uv = bf2f(uTb[o]);
    float zv = zs[j * 65 + dl];
    float ssz = zv * sigmoidf_(zv);
    qT[o] = make_float2(del, del * uv);
    unsigned lo = f2bf(uv * Dskip[d] * ssz);
    unsigned hi = f2bf(ssz);
    eT[o] = lo | (hi << 16);
  }
}

// ---------------- selective scan: wave per (b,d), lane = state; no barriers ----------------
// Per t: one b64 (del,delu) broadcast + one b32 (B,C pair) coalesced; 7 VALU + exp2.
__global__ __launch_bounds__(256)
void k_scan(const float2* __restrict__ qT, const unsigned* __restrict__ eT,
            const unsigned short* __restrict__ xdbl, const float* __restrict__ Alog,
            unsigned short* __restrict__ yTb) {
  int wave = threadIdx.x >> 6, lane = threadIdx.x & 63;
  int b = blockIdx.x / (DINNER / 4);
  int d = (blockIdx.x % (DINNER / 4)) * 4 + wave;
  __shared__ float ps_all[4][16 * 68];
  float* ps = ps_all[wave];               // per-wave region; same-wave DS ops are ordered
  float Al2 = -__expf(Alog[d * DSTATE + lane]) * 1.44269504088896340736f;
  size_t chan = ((size_t)b * DINNER + d) * TLEN;
  const float2* pq = qT + chan;
  const unsigned* pe = eT + chan;
  unsigned short* py = yTb + chan;
  // (B,C) pair dword for state=lane at row tok: dword index 6 + lane (row = 70 dwords)
  const unsigned* xb = (const unsigned*)(xdbl + (size_t)b * TLEN * XP) + 6 + lane;
  float h = 0.f;
  int tl = lane & 15, qq = lane >> 4;
  for (int t0 = 0; t0 < TLEN; t0 += 16) {
#pragma unroll
    for (int t = 0; t < 16; ++t) {
      float2 q = pq[t0 + t];
      unsigned bc = xb[(size_t)(t0 + t) * (XP / 2)];
      float Bv = bflo(bc), Cv = bfhi(bc);
      h = fmaf(h, exp2f(q.x * Al2), q.y * Bv);
      ps[t * 68 + lane] = h * Cv;
    }
    float p = 0.f;
    const floatx4* pr = (const floatx4*)&ps[tl * 68 + qq * 16];
#pragma unroll
    for (int i = 0; i < 4; ++i) {
      floatx4 v = pr[i];
      p += v[0] + v[1] + v[2] + v[3];
    }
    p += __shfl_xor(p, 16);
    p += __shfl_xor(p, 32);
    if (lane < 16) {
      int t = t0 + tl;
      unsigned e = pe[t];
      py[t] = f2bf(fmaf(p, bfhi(e), bflo(e)));
    }
  }
}

// ---- transpose yT_bf[b][d][t] -> y_bf[tok][d] (bf16 -> bf16) ----
__global__ __launch_bounds__(256)
void k_t2b(const unsigned short* __restrict__ yTb, unsigned short* __restrict__ ybf) {
  int t0 = blockIdx.x * 64, d0 = blockIdx.y * 64, b = blockIdx.z;
  __shared__ unsigned short ls[64 * 66];
  int tid = threadIdx.x, j = tid & 63, w = tid >> 6;
#pragma unroll
  for (int it = 0; it < 16; ++it) {
    int dl = it * 4 + w;
    ls[dl * 66 + j] = yTb[((size_t)b * DINNER + d0 + dl) * TLEN + t0 + j];
  }
  __syncthreads();
#pragma unroll
  for (int it = 0; it < 16; ++it) {
    int tr = it * 4 + w;
    ybf[((size_t)b * TLEN + t0 + tr) * DINNER + d0 + j] = ls[j * 66 + tr];
  }
}

// ---------------- head ----------------
__global__ __launch_bounds__(256)
void k_head(const float* __restrict__ h, const float* __restrict__ hw,
            const float* __restrict__ hb, float* __restrict__ out) {
  int tok = blockIdx.x * 4 + (threadIdx.x >> 6);
  int lane = threadIdx.x & 63;
  const float* hr = h + (size_t)tok * DMODEL;
  float s = hr[lane] * hw[lane] + hr[lane + 64] * hw[lane + 64];
  if (lane < DMODEL - 128) s += hr[lane + 128] * hw[lane + 128];
#pragma unroll
  for (int off = 32; off; off >>= 1) s += __shfl_xor(s, off);
  if (lane == 0) out[tok] = s + hb[0];
}

extern "C" void kernel_launch(void* const* d_in, const int* in_sizes, int n_in,
                              void* d_out, int out_size, void* d_ws, size_t ws_size,
                              hipStream_t stream) {
  const float* x      = (const float*)d_in[0];
  const float* pre_w  = (const float*)d_in[1];
  const float* pre_b  = (const float*)d_in[2];
  const float* ln_g   = (const float*)d_in[3];
  const float* ln_b   = (const float*)d_in[4];
  const float* in_w   = (const float*)d_in[5];
  const float* conv_w = (const float*)d_in[6];
  const float* conv_b = (const float*)d_in[7];
  const float* xproj_w= (const float*)d_in[8];
  const float* dt_w   = (const float*)d_in[9];
  const float* dt_b   = (const float*)d_in[10];
  const float* A_log  = (const float*)d_in[11];
  const float* D_skip = (const float*)d_in[12];
  const float* out_w  = (const float*)d_in[13];
  const float* head_w = (const float*)d_in[14];
  const float* head_b = (const float*)d_in[15];
  float* out = (float*)d_out;

  // workspace (float units), ~201 MB:
  // h | xdbl_bf (XP rows) | qT (float2; first region also serves lnxd_bf/u_bf before pack)
  // | uT_bf | X (xbuf fp32 -> eT -> y_bf) | Y (zbuf_bf -> yT_bf) | wbf (all 8 layers)
  float* ws = (float*)d_ws;
  float* h    = ws;
  unsigned short* xdbl_bf = (unsigned short*)(h + (size_t)NTOK * DMODEL);
  float2* qT  = (float2*)(xdbl_bf + (size_t)NTOK * XP);
  unsigned short* uT_bf = (unsigned short*)(qT + (size_t)NTOK * DINNER);
  float* X    = (float*)(uT_bf + (size_t)NTOK * DINNER);
  float* Y    = X + (size_t)NTOK * DINNER;
  unsigned short* wbf = (unsigned short*)(Y + (size_t)NTOK * DINNER / 2);

  unsigned short* lnxd_bf = (unsigned short*)qT;   // dead before pack writes qT
  unsigned short* u_bf    = (unsigned short*)qT;   // dead before pack writes qT
  float*          xbuf    = X;
  unsigned*       eT      = (unsigned*)X;          // xbuf dead after convT
  unsigned short* y_bf    = (unsigned short*)X;    // eT dead after scan
  unsigned short* zbuf_bf = (unsigned short*)Y;
  unsigned short* yT_bf   = (unsigned short*)Y;    // zbuf dead after pack

  k_preconv<<<NTOK * DMODEL / 256, 256, 0, stream>>>(x, pre_w, pre_b, h);
  k_cast<<<NBLK * 773, 256, 0, stream>>>(in_w, xproj_w, out_w, wbf);

  for (int L = 0; L < NBLK; ++L) {
    unsigned short* w_in = wbf + (size_t)L * WPL;
    unsigned short* w_xp = w_in + 102400;
    unsigned short* w_ou = w_in + 146560;
    k_ln<<<NTOK / 4, 256, 0, stream>>>(h, ln_g + L * DMODEL, ln_b + L * DMODEL, lnxd_bf);
    k_mm_in<<<dim3(5, NTOK / 128), 256, 0, stream>>>(lnxd_bf, w_in, xbuf, zbuf_bf);
    k_convT<<<dim3(TLEN / 64, DINNER / 64, BATCH), 256, 0, stream>>>(
        xbuf, conv_w + (size_t)L * DINNER * DCONV, conv_b + (size_t)L * DINNER,
        uT_bf, u_bf);
    k_mm_x<<<dim3(3, NTOK / 128), 256, 0, stream>>>(u_bf, w_xp, xdbl_bf);
    k_pack<<<dim3(TLEN / 64, DINNER / 64, BATCH), 256, 0, stream>>>(
        zbuf_bf, xdbl_bf, uT_bf, dt_w + (size_t)L * DINNER * DTRANK,
        dt_b + (size_t)L * DINNER, D_skip + (size_t)L * DINNER, qT, eT);
    k_scan<<<BATCH * (DINNER / 4), 256, 0, stream>>>(
        qT, eT, xdbl_bf, A_log + (size_t)L * DINNER * DSTATE, yT_bf);
    k_t2b<<<dim3(TLEN / 64, DINNER / 64, BATCH), 256, 0, stream>>>(yT_bf, y_bf);
    k_mm_g<<<dim3(3, NTOK / 128), 256, 0, stream>>>(y_bf, w_ou, h, h, DMODEL, DINNER);
  }

  k_head<<<NTOK / 4, 256, 0, stream>>>(h, head_w, head_b, out);
}